// Round 18
// baseline (2505.822 us; speedup 1.0000x reference)
//
#include <hip/hip_runtime.h>

typedef _Float16 half8 __attribute__((ext_vector_type(8)));
typedef float f32x4 __attribute__((ext_vector_type(4)));
typedef unsigned int u32x4 __attribute__((ext_vector_type(4)));

#define TT 512
#define HH 512
#define P32 0xFFFFFFFFu

// ws layout (bytes):
//   [0,        16777216)  x16   : [32 b][512 t][512 d] f16
//   [16777216, 50331648)  h_pk  : [2 dir][512 step][64 j][32 b][8 u] f16 (atomic-poisoned per launch)
//   [50331648, 50335744)  flags : [2 dir][8 slot][64 wg] int (epoch ring)
//   [50339840, 54534144)  Upk   : packed U frags f16 (2^21)
//   [54534144, 58728448)  Wpk   : packed W frags f16 (2^21)
#define OFF_HPK   16777216
#define OFF_FLAGS 50331648
#define OFF_UPK   50339840
#define OFF_WPK   54534144

struct BiasPtrs { const float* b[8]; };

struct PackParams {
  const float* U[8];
  const float* W[8];
  _Float16* Upk;
  _Float16* Wpk;
};

__global__ void convert_x_kernel(const float* __restrict__ x, _Float16* __restrict__ x16) {
  const size_t i = ((size_t)blockIdx.x * blockDim.x + threadIdx.x) * 8;
  float4 v0 = *(const float4*)(x + i);
  float4 v1 = *(const float4*)(x + i + 4);
  half8 h;
  h[0] = (_Float16)v0.x; h[1] = (_Float16)v0.y; h[2] = (_Float16)v0.z; h[3] = (_Float16)v0.w;
  h[4] = (_Float16)v1.x; h[5] = (_Float16)v1.y; h[6] = (_Float16)v1.z; h[7] = (_Float16)v1.w;
  *(half8*)(x16 + i) = h;
}

// Pack U/W into MFMA B-fragment order:
// idx = ((((d*64 + j)*2 + ct)*16 + kt)*64 + l)*8 + jj
// lane l: r15=l&15, kg=l>>4; col -> g=r15&3, u=j*8+ct*4+(r15>>2); k=kt*32+kg*8+jj.
__global__ void pack_frags_kernel(PackParams p) {
  const unsigned n = blockIdx.x * 256 + threadIdx.x;   // 2 * 2^21 total
  const unsigned o = n & 2097151u;
  const int sel = n >> 21;                              // 0 = U, 1 = W
  const int jj = o & 7, l = (o >> 3) & 63, kt = (o >> 9) & 15;
  const int ct = (o >> 13) & 1, j = (o >> 14) & 63, d = (o >> 20) & 1;
  const int r15 = l & 15, kg = l >> 4;
  const int g = r15 & 3;
  const int u = j * 8 + ct * 4 + (r15 >> 2);
  const int k = kt * 32 + kg * 8 + jj;
  const float* M = sel ? p.W[4 * d + g] : p.U[4 * d + g];
  _Float16* dst = sel ? p.Wpk : p.Upk;
  dst[o] = (_Float16)M[k * HH + u];
}

// Poison h_pk with AGENT-ATOMIC stores: poison lives at the coherence point,
// never as dirty/clean lines in any XCD L2 (the R10 failure hole).
__global__ void poison_kernel(unsigned long long* __restrict__ p) {
  const unsigned i = (blockIdx.x * 256 + threadIdx.x) * 4;
#pragma unroll
  for (int k = 0; k < 4; ++k)
    __hip_atomic_store(p + i + k, 0xFFFFFFFFFFFFFFFFull,
                       __ATOMIC_RELAXED, __HIP_MEMORY_SCOPE_AGENT);
}

// Zero flags with AGENT-ATOMIC stores (no dirty L2 lines over live flags).
__global__ void zero_flags_kernel(int* __restrict__ p) {
  __hip_atomic_store(p + blockIdx.x * 256 + threadIdx.x, 0,
                     __ATOMIC_RELAXED, __HIP_MEMORY_SCOPE_AGENT);
}

__device__ __forceinline__ float hsig(float x) {
  return fminf(fmaxf(fmaf(x, 0.2f, 0.5f), 0.0f), 1.0f);
}

__device__ __forceinline__ float fast_tanh(float x) {
  const float e = __expf(2.0f * x);
  return fmaf(-2.0f, __builtin_amdgcn_rcpf(e + 1.0f), 1.0f);
}

// 128 WGs x 256 thr (cooperative). WG = (d = bid&1, j = bid>>1) (parity
// mapping: R16/R17-measured FETCH 263->136MB). WG owns units [j*8, j*8+8)
// x 4 gates = 32 cols; wave w: rows rt=(w&1)*16, cols ct=(w>>1)*16, K=512.
// Weights LDS-resident.
// DRAIN-FREE publish protocol: h_pk is atomic-poisoned (0xFFFFFFFF dwords)
// before the scan. Publish = 64x8B agent-atomic h stores + flag store with NO
// vmcnt between (flag = timing gate only). Consume = flag-gated bulk
// nontemporal dwordx4 loads (no L2 allocate -> cannot cache stale poison) +
// per-dword 4B poison verify + agent-atomic retry for stragglers (4B writes
// cannot tear; h in (-1,1) so a data dword is never 0xFFFFFFFF).
__global__ __launch_bounds__(256, 1) void lstm_scan_kernel(
    const _Float16* __restrict__ x16,
    _Float16* __restrict__ h_pk,
    int* __restrict__ flags,
    const _Float16* __restrict__ Upk,
    const _Float16* __restrict__ Wpk,
    BiasPtrs bp) {
  const int tid = threadIdx.x;
  const int bid = blockIdx.x;
  const int d   = bid & 1;
  const int j   = bid >> 1;
  const int w   = tid >> 6;
  const int l   = tid & 63;
  const int r15 = l & 15;
  const int kg  = l >> 4;
  const int rt  = w & 1;
  const int ct  = w >> 1;
  const int arow = rt * 16 + r15;

  __shared__ __align__(16) half8 ulds[2 * 16 * 64];   // 32 KB, [ct][kt][l]
  __shared__ __align__(16) half8 wlds[2 * 16 * 64];   // 32 KB
  __shared__ __align__(16) float zlds[32 * 36];
  __shared__ __align__(16) unsigned short hlds[256];

  // Stage this WG's weight fragments into LDS once (rt==0 waves cover both ct).
  {
    const half8* ub = (const half8*)Upk;
    const half8* wb = (const half8*)Wpk;
    const int base = (((d * 64 + j) * 2 + ct) * 16) * 64 + l;
    if (rt == 0) {
#pragma unroll
      for (int kt = 0; kt < 16; ++kt) {
        ulds[(ct * 16 + kt) * 64 + l] = ub[base + kt * 64];
        wlds[(ct * 16 + kt) * 64 + l] = wb[base + kt * 64];
      }
    }
  }

  const int b_e  = tid >> 3;
  const int uu_e = tid & 7;
  const int u_e  = j * 8 + uu_e;
  const int slot_e = (uu_e >> 2) * 16 + (uu_e & 3) * 4;
  f32x4 biasv;
#pragma unroll
  for (int g = 0; g < 4; ++g) biasv[g] = bp.b[4 * d + g][u_e];

  __syncthreads();   // weights staged

  float c = 0.0f;

  for (int s = 0; s < TT; ++s) {
    const int t = d ? (TT - 1 - s) : s;

    // 1) Issue x_t fragment loads (plain; fetch hides under the poll).
    half8 xa[16];
    {
      const half8* xb = (const half8*)(x16 + ((size_t)arow * TT + t) * HH);
#pragma unroll
      for (int kt = 0; kt < 16; ++kt) xa[kt] = xb[kt * 4 + kg];
    }
    __builtin_amdgcn_sched_barrier(0);

    // 2) Poll producer flags: wave 0 only, 64-lane coalesced, throttled.
    //    Flag is a timing gate; data correctness comes from the sentinel.
    if (s > 0) {
      if (tid < 64) {
        const int* fl = flags + ((d * 8 + ((s - 1) & 7)) << 6) + tid;
        while (__hip_atomic_load(fl, __ATOMIC_RELAXED, __HIP_MEMORY_SCOPE_AGENT) < s) {
          __builtin_amdgcn_s_sleep(1);
        }
      }
      __syncthreads();
    }
    __builtin_amdgcn_sched_barrier(0);

    // 3) Issue h(s-1) bulk loads: nontemporal dwordx4 (no L2 allocate).
    u32x4 hv[16];
    const u32x4* hb4 = (const u32x4*)(h_pk + (size_t)(d * TT + (s > 0 ? s - 1 : 0)) * 16384);
    if (s > 0) {
#pragma unroll
      for (int kt = 0; kt < 16; ++kt)
        hv[kt] = __builtin_nontemporal_load(hb4 + (kt * 4 + kg) * 32 + arow);
    }
    __builtin_amdgcn_sched_barrier(0);

    // 4) x_t @ W from LDS weights — executes while h loads are in flight.
    f32x4 acc0 = {0,0,0,0}, acc1 = {0,0,0,0}, acc2 = {0,0,0,0}, acc3 = {0,0,0,0};
#pragma unroll
    for (int kt = 0; kt < 16; ++kt) {
      const half8 wk = wlds[(ct * 16 + kt) * 64 + l];
      if ((kt & 3) == 0)      acc0 = __builtin_amdgcn_mfma_f32_16x16x32_f16(xa[kt], wk, acc0, 0, 0, 0);
      else if ((kt & 3) == 1) acc1 = __builtin_amdgcn_mfma_f32_16x16x32_f16(xa[kt], wk, acc1, 0, 0, 0);
      else if ((kt & 3) == 2) acc2 = __builtin_amdgcn_mfma_f32_16x16x32_f16(xa[kt], wk, acc2, 0, 0, 0);
      else                    acc3 = __builtin_amdgcn_mfma_f32_16x16x32_f16(xa[kt], wk, acc3, 0, 0, 0);
    }
    __builtin_amdgcn_sched_barrier(0);

    // 5) Verify each h dword (4B granule — cannot tear); retry stragglers via
    //    agent-atomic (bypasses caches, livelock-impossible); then h@U.
    if (s > 0) {
#pragma unroll
      for (int kt = 0; kt < 16; ++kt) {
        u32x4 v = hv[kt];
        if (v[0] == P32 || v[1] == P32 || v[2] == P32 || v[3] == P32) {
          const unsigned* q = (const unsigned*)(hb4 + (kt * 4 + kg) * 32 + arow);
          while (v[0] == P32) v[0] = __hip_atomic_load(q + 0, __ATOMIC_RELAXED, __HIP_MEMORY_SCOPE_AGENT);
          while (v[1] == P32) v[1] = __hip_atomic_load(q + 1, __ATOMIC_RELAXED, __HIP_MEMORY_SCOPE_AGENT);
          while (v[2] == P32) v[2] = __hip_atomic_load(q + 2, __ATOMIC_RELAXED, __HIP_MEMORY_SCOPE_AGENT);
          while (v[3] == P32) v[3] = __hip_atomic_load(q + 3, __ATOMIC_RELAXED, __HIP_MEMORY_SCOPE_AGENT);
        }
        const half8 a  = __builtin_bit_cast(half8, v);
        const half8 uk = ulds[(ct * 16 + kt) * 64 + l];
        if ((kt & 3) == 0)      acc0 = __builtin_amdgcn_mfma_f32_16x16x32_f16(a, uk, acc0, 0, 0, 0);
        else if ((kt & 3) == 1) acc1 = __builtin_amdgcn_mfma_f32_16x16x32_f16(a, uk, acc1, 0, 0, 0);
        else if ((kt & 3) == 2) acc2 = __builtin_amdgcn_mfma_f32_16x16x32_f16(a, uk, acc2, 0, 0, 0);
        else                    acc3 = __builtin_amdgcn_mfma_f32_16x16x32_f16(a, uk, acc3, 0, 0, 0);
      }
    }
    const f32x4 z = (acc0 + acc1) + (acc2 + acc3);

    // 6) z -> LDS. D-frag: col = r15, row = kg*4 + i.
#pragma unroll
    for (int i = 0; i < 4; ++i)
      zlds[(rt * 16 + kg * 4 + i) * 36 + ct * 16 + r15] = z[i];
    __syncthreads();

    // 7) Elementwise LSTM cell.
    f32x4 pre = *(const f32x4*)&zlds[(size_t)b_e * 36 + slot_e] + biasv;
    const float ig = hsig(pre[0]);
    const float fg = hsig(pre[1]);
    const float gg = fast_tanh(pre[2]);
    const float og = hsig(pre[3]);
    c = fg * c + ig * gg;
    const float h = og * fast_tanh(c);

    hlds[tid] = __builtin_bit_cast(unsigned short, (_Float16)h);
    __syncthreads();

    // 8) Publish, DRAIN-FREE: h stores and flag store fire back-to-back.
    //    Sentinel verification makes data-before-flag ordering unnecessary.
    if (tid < 64) {
      const unsigned long long v = ((const unsigned long long*)hlds)[tid];
      unsigned long long* dst = (unsigned long long*)h_pk +
                                ((size_t)(d * TT + s) * 64 + j) * 64 + tid;
      __hip_atomic_store(dst, v, __ATOMIC_RELAXED, __HIP_MEMORY_SCOPE_AGENT);
      if (tid == 0)
        __hip_atomic_store(flags + ((d * 8 + (s & 7)) << 6) + j, s + 1,
                           __ATOMIC_RELAXED, __HIP_MEMORY_SCOPE_AGENT);
    }
  }
}

// out[b][t][u] = h_fwd[t] + h_bwd[t]  (Theano: backward stacked in iteration
// order without re-reversing; scan stored bwd iteration s at slot s).
// Safe: scan fully completes before this dispatch; dispatch boundary performs
// L2 writeback+invalidate (proven by every cross-kernel read in this session).
__global__ void sum_out_kernel(const _Float16* __restrict__ h_pk, float* __restrict__ out) {
  const unsigned idx = blockIdx.x * 256 + threadIdx.x;   // 32*512*64
  const int j = idx & 63;
  const int t = (idx >> 6) & 511;
  const int b = idx >> 15;
  half8 hf = ((const half8*)h_pk)[((size_t)t * 64 + j) * 32 + b];
  half8 hg = ((const half8*)h_pk)[((size_t)(TT + t) * 64 + j) * 32 + b];
  float* o = out + (((size_t)b * TT + t) * HH + j * 8);
  float4 r0, r1;
  r0.x = (float)hf[0] + (float)hg[0]; r0.y = (float)hf[1] + (float)hg[1];
  r0.z = (float)hf[2] + (float)hg[2]; r0.w = (float)hf[3] + (float)hg[3];
  r1.x = (float)hf[4] + (float)hg[4]; r1.y = (float)hf[5] + (float)hg[5];
  r1.z = (float)hf[6] + (float)hg[6]; r1.w = (float)hf[7] + (float)hg[7];
  *(float4*)o = r0;
  *(float4*)(o + 4) = r1;
}

extern "C" void kernel_launch(void* const* d_in, const int* in_sizes, int n_in,
                              void* d_out, int out_size, void* d_ws, size_t ws_size,
                              hipStream_t stream) {
  (void)in_sizes; (void)n_in; (void)out_size; (void)ws_size;
  char* ws = (char*)d_ws;
  _Float16* x16   = (_Float16*)ws;
  _Float16* h_pk  = (_Float16*)(ws + OFF_HPK);
  int*      flags = (int*)(ws + OFF_FLAGS);
  _Float16* Upk   = (_Float16*)(ws + OFF_UPK);
  _Float16* Wpk   = (_Float16*)(ws + OFF_WPK);

  convert_x_kernel<<<4096, 256, 0, stream>>>((const float*)d_in[0], x16);

  PackParams pp;
  for (int g = 0; g < 8; ++g) {
    pp.W[g] = (const float*)d_in[1 + g];
    pp.U[g] = (const float*)d_in[9 + g];
  }
  pp.Upk = Upk; pp.Wpk = Wpk;
  pack_frags_kernel<<<16384, 256, 0, stream>>>(pp);

  // Atomic poison fill: 33554432 B = 4194304 ull = 4096 blocks * 256 thr * 4.
  poison_kernel<<<4096, 256, 0, stream>>>((unsigned long long*)(ws + OFF_HPK));

  zero_flags_kernel<<<4, 256, 0, stream>>>(flags);   // 1024 ints, atomic stores

  BiasPtrs bp;
  for (int g = 0; g < 8; ++g) bp.b[g] = (const float*)d_in[17 + g];

  void* args[] = { (void*)&x16, (void*)&h_pk, (void*)&flags,
                   (void*)&Upk, (void*)&Wpk, (void*)&bp };
  hipLaunchCooperativeKernel((const void*)lstm_scan_kernel, dim3(128), dim3(256),
                             args, 0, stream);

  sum_out_kernel<<<4096, 256, 0, stream>>>(h_pk, (float*)d_out);
}

// Round 19
// 2154.477 us; speedup vs baseline: 1.1631x; 1.1631x over previous
//
#include <hip/hip_runtime.h>

typedef _Float16 half8 __attribute__((ext_vector_type(8)));
typedef float f32x4 __attribute__((ext_vector_type(4)));
typedef unsigned int u32x4 __attribute__((ext_vector_type(4)));

#define TT 512
#define HH 512
#define P32 0xFFFFFFFFu

// ws layout (bytes):
//   [0,        16777216)  x16   : [32 b][512 t][512 d] f16
//   [16777216, 50331648)  h_pk  : [2 dir][512 step][64 j][32 b][8 u] f16 (atomic-poisoned per launch)
//   [50331648, 50335744)  flags : [2 dir][8 slot][64 wg] int (epoch ring)
//   [50339840, 54534144)  Upk   : packed U frags f16 (2^21)
//   [54534144, 58728448)  Wpk   : packed W frags f16 (2^21)
#define OFF_HPK   16777216
#define OFF_FLAGS 50331648
#define OFF_UPK   50339840
#define OFF_WPK   54534144

struct BiasPtrs { const float* b[8]; };

struct PackParams {
  const float* U[8];
  const float* W[8];
  _Float16* Upk;
  _Float16* Wpk;
};

__global__ void convert_x_kernel(const float* __restrict__ x, _Float16* __restrict__ x16) {
  const size_t i = ((size_t)blockIdx.x * blockDim.x + threadIdx.x) * 8;
  float4 v0 = *(const float4*)(x + i);
  float4 v1 = *(const float4*)(x + i + 4);
  half8 h;
  h[0] = (_Float16)v0.x; h[1] = (_Float16)v0.y; h[2] = (_Float16)v0.z; h[3] = (_Float16)v0.w;
  h[4] = (_Float16)v1.x; h[5] = (_Float16)v1.y; h[6] = (_Float16)v1.z; h[7] = (_Float16)v1.w;
  *(half8*)(x16 + i) = h;
}

// Pack U/W into MFMA B-fragment order:
// idx = ((((d*64 + j)*2 + ct)*16 + kt)*64 + l)*8 + jj
// lane l: r15=l&15, kg=l>>4; col -> g=r15&3, u=j*8+ct*4+(r15>>2); k=kt*32+kg*8+jj.
__global__ void pack_frags_kernel(PackParams p) {
  const unsigned n = blockIdx.x * 256 + threadIdx.x;   // 2 * 2^21 total
  const unsigned o = n & 2097151u;
  const int sel = n >> 21;                              // 0 = U, 1 = W
  const int jj = o & 7, l = (o >> 3) & 63, kt = (o >> 9) & 15;
  const int ct = (o >> 13) & 1, j = (o >> 14) & 63, d = (o >> 20) & 1;
  const int r15 = l & 15, kg = l >> 4;
  const int g = r15 & 3;
  const int u = j * 8 + ct * 4 + (r15 >> 2);
  const int k = kt * 32 + kg * 8 + jj;
  const float* M = sel ? p.W[4 * d + g] : p.U[4 * d + g];
  _Float16* dst = sel ? p.Wpk : p.Upk;
  dst[o] = (_Float16)M[k * HH + u];
}

// Poison h_pk with AGENT-ATOMIC stores: poison lives at the coherence point,
// never as DIRTY lines in any XCD L2 (the R10 failure hole: memset's dirty
// poison lines evicted over real data post-publish).
__global__ void poison_kernel(unsigned long long* __restrict__ p) {
  const unsigned i = (blockIdx.x * 256 + threadIdx.x) * 4;
#pragma unroll
  for (int k = 0; k < 4; ++k)
    __hip_atomic_store(p + i + k, 0xFFFFFFFFFFFFFFFFull,
                       __ATOMIC_RELAXED, __HIP_MEMORY_SCOPE_AGENT);
}

// Zero flags with AGENT-ATOMIC stores (no dirty L2 lines over live flags).
__global__ void zero_flags_kernel(int* __restrict__ p) {
  __hip_atomic_store(p + blockIdx.x * 256 + threadIdx.x, 0,
                     __ATOMIC_RELAXED, __HIP_MEMORY_SCOPE_AGENT);
}

__device__ __forceinline__ float hsig(float x) {
  return fminf(fmaxf(fmaf(x, 0.2f, 0.5f), 0.0f), 1.0f);
}

__device__ __forceinline__ float fast_tanh(float x) {
  const float e = __expf(2.0f * x);
  return fmaf(-2.0f, __builtin_amdgcn_rcpf(e + 1.0f), 1.0f);
}

// 128 WGs x 256 thr (cooperative). WG = (d = bid&1, j = bid>>1) (parity
// mapping: R16/R17-measured FETCH 263->136MB). WG owns units [j*8, j*8+8)
// x 4 gates = 32 cols; wave w: rows rt=(w&1)*16, cols ct=(w>>1)*16, K=512.
// Weights LDS-resident.
// DRAIN-FREE publish + PLAIN-LOAD consume: h_pk atomic-poisoned before the
// scan. Publish = 64x8B agent-atomic h stores + flag store, NO vmcnt between
// (flag = timing hint). Consume = flag-gated plain dwordx4 loads (XCD-L2
// dedup preserved) + per-dword 4B poison verify + agent-atomic retry for
// stragglers (4B granule cannot tear; h in (-1,1) so data != poison; clean
// stale-poison L2 lines are handled by the retry and invalidated at the next
// dispatch boundary, so sum_out sees real data).
__global__ __launch_bounds__(256, 1) void lstm_scan_kernel(
    const _Float16* __restrict__ x16,
    _Float16* __restrict__ h_pk,
    int* __restrict__ flags,
    const _Float16* __restrict__ Upk,
    const _Float16* __restrict__ Wpk,
    BiasPtrs bp) {
  const int tid = threadIdx.x;
  const int bid = blockIdx.x;
  const int d   = bid & 1;
  const int j   = bid >> 1;
  const int w   = tid >> 6;
  const int l   = tid & 63;
  const int r15 = l & 15;
  const int kg  = l >> 4;
  const int rt  = w & 1;
  const int ct  = w >> 1;
  const int arow = rt * 16 + r15;

  __shared__ __align__(16) half8 ulds[2 * 16 * 64];   // 32 KB, [ct][kt][l]
  __shared__ __align__(16) half8 wlds[2 * 16 * 64];   // 32 KB
  __shared__ __align__(16) float zlds[32 * 36];
  __shared__ __align__(16) unsigned short hlds[256];

  // Stage this WG's weight fragments into LDS once (rt==0 waves cover both ct).
  {
    const half8* ub = (const half8*)Upk;
    const half8* wb = (const half8*)Wpk;
    const int base = (((d * 64 + j) * 2 + ct) * 16) * 64 + l;
    if (rt == 0) {
#pragma unroll
      for (int kt = 0; kt < 16; ++kt) {
        ulds[(ct * 16 + kt) * 64 + l] = ub[base + kt * 64];
        wlds[(ct * 16 + kt) * 64 + l] = wb[base + kt * 64];
      }
    }
  }

  const int b_e  = tid >> 3;
  const int uu_e = tid & 7;
  const int u_e  = j * 8 + uu_e;
  const int slot_e = (uu_e >> 2) * 16 + (uu_e & 3) * 4;
  f32x4 biasv;
#pragma unroll
  for (int g = 0; g < 4; ++g) biasv[g] = bp.b[4 * d + g][u_e];

  __syncthreads();   // weights staged

  float c = 0.0f;

  for (int s = 0; s < TT; ++s) {
    const int t = d ? (TT - 1 - s) : s;

    // 1) Issue x_t fragment loads (plain; fetch hides under the poll).
    half8 xa[16];
    {
      const half8* xb = (const half8*)(x16 + ((size_t)arow * TT + t) * HH);
#pragma unroll
      for (int kt = 0; kt < 16; ++kt) xa[kt] = xb[kt * 4 + kg];
    }
    __builtin_amdgcn_sched_barrier(0);

    // 2) Poll producer flags: wave 0 only, 64-lane coalesced, throttled.
    //    Flag is a timing hint; data correctness comes from the sentinel.
    if (s > 0) {
      if (tid < 64) {
        const int* fl = flags + ((d * 8 + ((s - 1) & 7)) << 6) + tid;
        while (__hip_atomic_load(fl, __ATOMIC_RELAXED, __HIP_MEMORY_SCOPE_AGENT) < s) {
          __builtin_amdgcn_s_sleep(1);
        }
      }
      __syncthreads();
    }
    __builtin_amdgcn_sched_barrier(0);

    // 3) Issue h(s-1) PLAIN dwordx4 loads (XCD-L2 dedup across same-L2 WGs).
    u32x4 hv[16];
    const u32x4* hb4 = (const u32x4*)(h_pk + (size_t)(d * TT + (s > 0 ? s - 1 : 0)) * 16384);
    if (s > 0) {
#pragma unroll
      for (int kt = 0; kt < 16; ++kt)
        hv[kt] = hb4[(kt * 4 + kg) * 32 + arow];
    }
    __builtin_amdgcn_sched_barrier(0);

    // 4) x_t @ W from LDS weights — executes while h loads are in flight.
    f32x4 acc0 = {0,0,0,0}, acc1 = {0,0,0,0}, acc2 = {0,0,0,0}, acc3 = {0,0,0,0};
#pragma unroll
    for (int kt = 0; kt < 16; ++kt) {
      const half8 wk = wlds[(ct * 16 + kt) * 64 + l];
      if ((kt & 3) == 0)      acc0 = __builtin_amdgcn_mfma_f32_16x16x32_f16(xa[kt], wk, acc0, 0, 0, 0);
      else if ((kt & 3) == 1) acc1 = __builtin_amdgcn_mfma_f32_16x16x32_f16(xa[kt], wk, acc1, 0, 0, 0);
      else if ((kt & 3) == 2) acc2 = __builtin_amdgcn_mfma_f32_16x16x32_f16(xa[kt], wk, acc2, 0, 0, 0);
      else                    acc3 = __builtin_amdgcn_mfma_f32_16x16x32_f16(xa[kt], wk, acc3, 0, 0, 0);
    }
    __builtin_amdgcn_sched_barrier(0);

    // 5) Verify each h dword (4B granule — cannot tear); retry stragglers via
    //    agent-atomic (bypasses caches, converges); then h@U from LDS.
    if (s > 0) {
#pragma unroll
      for (int kt = 0; kt < 16; ++kt) {
        u32x4 v = hv[kt];
        if (v[0] == P32 || v[1] == P32 || v[2] == P32 || v[3] == P32) {
          const unsigned* q = (const unsigned*)(hb4 + (kt * 4 + kg) * 32 + arow);
          while (v[0] == P32) v[0] = __hip_atomic_load(q + 0, __ATOMIC_RELAXED, __HIP_MEMORY_SCOPE_AGENT);
          while (v[1] == P32) v[1] = __hip_atomic_load(q + 1, __ATOMIC_RELAXED, __HIP_MEMORY_SCOPE_AGENT);
          while (v[2] == P32) v[2] = __hip_atomic_load(q + 2, __ATOMIC_RELAXED, __HIP_MEMORY_SCOPE_AGENT);
          while (v[3] == P32) v[3] = __hip_atomic_load(q + 3, __ATOMIC_RELAXED, __HIP_MEMORY_SCOPE_AGENT);
        }
        const half8 a  = __builtin_bit_cast(half8, v);
        const half8 uk = ulds[(ct * 16 + kt) * 64 + l];
        if ((kt & 3) == 0)      acc0 = __builtin_amdgcn_mfma_f32_16x16x32_f16(a, uk, acc0, 0, 0, 0);
        else if ((kt & 3) == 1) acc1 = __builtin_amdgcn_mfma_f32_16x16x32_f16(a, uk, acc1, 0, 0, 0);
        else if ((kt & 3) == 2) acc2 = __builtin_amdgcn_mfma_f32_16x16x32_f16(a, uk, acc2, 0, 0, 0);
        else                    acc3 = __builtin_amdgcn_mfma_f32_16x16x32_f16(a, uk, acc3, 0, 0, 0);
      }
    }
    const f32x4 z = (acc0 + acc1) + (acc2 + acc3);

    // 6) z -> LDS. D-frag: col = r15, row = kg*4 + i.
#pragma unroll
    for (int i = 0; i < 4; ++i)
      zlds[(rt * 16 + kg * 4 + i) * 36 + ct * 16 + r15] = z[i];
    __syncthreads();

    // 7) Elementwise LSTM cell.
    f32x4 pre = *(const f32x4*)&zlds[(size_t)b_e * 36 + slot_e] + biasv;
    const float ig = hsig(pre[0]);
    const float fg = hsig(pre[1]);
    const float gg = fast_tanh(pre[2]);
    const float og = hsig(pre[3]);
    c = fg * c + ig * gg;
    const float h = og * fast_tanh(c);

    hlds[tid] = __builtin_bit_cast(unsigned short, (_Float16)h);
    __syncthreads();

    // 8) Publish, DRAIN-FREE: h stores and flag store fire back-to-back.
    //    Sentinel verification makes data-before-flag ordering unnecessary.
    if (tid < 64) {
      const unsigned long long v = ((const unsigned long long*)hlds)[tid];
      unsigned long long* dst = (unsigned long long*)h_pk +
                                ((size_t)(d * TT + s) * 64 + j) * 64 + tid;
      __hip_atomic_store(dst, v, __ATOMIC_RELAXED, __HIP_MEMORY_SCOPE_AGENT);
      if (tid == 0)
        __hip_atomic_store(flags + ((d * 8 + (s & 7)) << 6) + j, s + 1,
                           __ATOMIC_RELAXED, __HIP_MEMORY_SCOPE_AGENT);
    }
  }
}

// out[b][t][u] = h_fwd[t] + h_bwd[t]  (Theano: backward stacked in iteration
// order without re-reversing; scan stored bwd iteration s at slot s).
// Safe: new dispatch invalidates clean stale lines; all poison writes were
// agent-atomic so no dirty poison lines can overwrite data post-scan.
__global__ void sum_out_kernel(const _Float16* __restrict__ h_pk, float* __restrict__ out) {
  const unsigned idx = blockIdx.x * 256 + threadIdx.x;   // 32*512*64
  const int j = idx & 63;
  const int t = (idx >> 6) & 511;
  const int b = idx >> 15;
  half8 hf = ((const half8*)h_pk)[((size_t)t * 64 + j) * 32 + b];
  half8 hg = ((const half8*)h_pk)[((size_t)(TT + t) * 64 + j) * 32 + b];
  float* o = out + (((size_t)b * TT + t) * HH + j * 8);
  float4 r0, r1;
  r0.x = (float)hf[0] + (float)hg[0]; r0.y = (float)hf[1] + (float)hg[1];
  r0.z = (float)hf[2] + (float)hg[2]; r0.w = (float)hf[3] + (float)hg[3];
  r1.x = (float)hf[4] + (float)hg[4]; r1.y = (float)hf[5] + (float)hg[5];
  r1.z = (float)hf[6] + (float)hg[6]; r1.w = (float)hf[7] + (float)hg[7];
  *(float4*)o = r0;
  *(float4*)(o + 4) = r1;
}

extern "C" void kernel_launch(void* const* d_in, const int* in_sizes, int n_in,
                              void* d_out, int out_size, void* d_ws, size_t ws_size,
                              hipStream_t stream) {
  (void)in_sizes; (void)n_in; (void)out_size; (void)ws_size;
  char* ws = (char*)d_ws;
  _Float16* x16   = (_Float16*)ws;
  _Float16* h_pk  = (_Float16*)(ws + OFF_HPK);
  int*      flags = (int*)(ws + OFF_FLAGS);
  _Float16* Upk   = (_Float16*)(ws + OFF_UPK);
  _Float16* Wpk   = (_Float16*)(ws + OFF_WPK);

  convert_x_kernel<<<4096, 256, 0, stream>>>((const float*)d_in[0], x16);

  PackParams pp;
  for (int g = 0; g < 8; ++g) {
    pp.W[g] = (const float*)d_in[1 + g];
    pp.U[g] = (const float*)d_in[9 + g];
  }
  pp.Upk = Upk; pp.Wpk = Wpk;
  pack_frags_kernel<<<16384, 256, 0, stream>>>(pp);

  // Atomic poison fill: 33554432 B = 4194304 ull = 4096 blocks * 256 thr * 4.
  poison_kernel<<<4096, 256, 0, stream>>>((unsigned long long*)(ws + OFF_HPK));

  zero_flags_kernel<<<4, 256, 0, stream>>>(flags);   // 1024 ints, atomic stores

  BiasPtrs bp;
  for (int g = 0; g < 8; ++g) bp.b[g] = (const float*)d_in[17 + g];

  void* args[] = { (void*)&x16, (void*)&h_pk, (void*)&flags,
                   (void*)&Upk, (void*)&Wpk, (void*)&bp };
  hipLaunchCooperativeKernel((const void*)lstm_scan_kernel, dim3(128), dim3(256),
                             args, 0, stream);

  sum_out_kernel<<<4096, 256, 0, stream>>>(h_pk, (float*)d_out);
}

// Round 20
// 1773.402 us; speedup vs baseline: 1.4130x; 1.2149x over previous
//
#include <hip/hip_runtime.h>

typedef _Float16 half8 __attribute__((ext_vector_type(8)));
typedef float f32x4 __attribute__((ext_vector_type(4)));

#define TT 512
#define HH 512

// ws layout (bytes):
//   [0,        16777216)  x16   : [32 b][512 t][512 d] f16
//   [16777216, 50331648)  h_pk  : [2 dir][512 step][64 j][32 b][8 u] f16
//   [50331648, 50335744)  flags : [2 dir][8 slot][64 wg] int (epoch ring)
//   [50339840, 54534144)  Upk   : packed U frags f16 (2^21)
//   [54534144, 58728448)  Wpk   : packed W frags f16 (2^21)
#define OFF_HPK   16777216
#define OFF_FLAGS 50331648
#define OFF_UPK   50339840
#define OFF_WPK   54534144

struct BiasPtrs { const float* b[8]; };

struct PackParams {
  const float* U[8];
  const float* W[8];
  _Float16* Upk;
  _Float16* Wpk;
};

__global__ void convert_x_kernel(const float* __restrict__ x, _Float16* __restrict__ x16) {
  const size_t i = ((size_t)blockIdx.x * blockDim.x + threadIdx.x) * 8;
  float4 v0 = *(const float4*)(x + i);
  float4 v1 = *(const float4*)(x + i + 4);
  half8 h;
  h[0] = (_Float16)v0.x; h[1] = (_Float16)v0.y; h[2] = (_Float16)v0.z; h[3] = (_Float16)v0.w;
  h[4] = (_Float16)v1.x; h[5] = (_Float16)v1.y; h[6] = (_Float16)v1.z; h[7] = (_Float16)v1.w;
  *(half8*)(x16 + i) = h;
}

// Pack U/W into MFMA B-fragment order:
// idx = ((((d*64 + j)*2 + ct)*16 + kt)*64 + l)*8 + jj
// lane l: r15=l&15, kg=l>>4; col -> g=r15&3, u=j*8+ct*4+(r15>>2); k=kt*32+kg*8+jj.
__global__ void pack_frags_kernel(PackParams p) {
  const unsigned n = blockIdx.x * 256 + threadIdx.x;   // 2 * 2^21 total
  const unsigned o = n & 2097151u;
  const int sel = n >> 21;                              // 0 = U, 1 = W
  const int jj = o & 7, l = (o >> 3) & 63, kt = (o >> 9) & 15;
  const int ct = (o >> 13) & 1, j = (o >> 14) & 63, d = (o >> 20) & 1;
  const int r15 = l & 15, kg = l >> 4;
  const int g = r15 & 3;
  const int u = j * 8 + ct * 4 + (r15 >> 2);
  const int k = kt * 32 + kg * 8 + jj;
  const float* M = sel ? p.W[4 * d + g] : p.U[4 * d + g];
  _Float16* dst = sel ? p.Wpk : p.Upk;
  dst[o] = (_Float16)M[k * HH + u];
}

// Zero flags with AGENT-ATOMIC stores (no dirty L2 lines over live flags).
__global__ void zero_flags_kernel(int* __restrict__ p) {
  __hip_atomic_store(p + blockIdx.x * 256 + threadIdx.x, 0,
                     __ATOMIC_RELAXED, __HIP_MEMORY_SCOPE_AGENT);
}

__device__ __forceinline__ float hsig(float x) {
  return fminf(fmaxf(fmaf(x, 0.2f, 0.5f), 0.0f), 1.0f);
}

__device__ __forceinline__ float fast_tanh(float x) {
  const float e = __expf(2.0f * x);
  return fmaf(-2.0f, __builtin_amdgcn_rcpf(e + 1.0f), 1.0f);
}

// 128 WGs x 256 thr (cooperative). WG = (d = bid>>6, j = bid&63) owns units
// [j*8, j*8+8) x 4 gates = 32 cols. Wave w: rows rt=(w&1)*16, cols ct=(w>>1)*16,
// full K=512.
// Weights live in LDS (staged once; ds_read ~12cy per use) — eliminates the
// per-step 64KB/WG weight refetch that thrashed XCD L2 (rounds 3-8) and put
// L3/HBM-class legs on the critical path.
// Sync (best-measured, R12): parallel per-WG epoch flags (ring 8), wave-0
// 64-lane coalesced poll with s_sleep throttle + barrier release; publish =
// wave-0 agent-atomic h stores + vmcnt(0) drain + flag store. Consume =
// plain dwordx4 h loads (XCD-L2 dedup). x@W overlaps the h round trip.
__global__ __launch_bounds__(256, 1) void lstm_scan_kernel(
    const _Float16* __restrict__ x16,
    _Float16* __restrict__ h_pk,
    int* __restrict__ flags,
    const _Float16* __restrict__ Upk,
    const _Float16* __restrict__ Wpk,
    BiasPtrs bp) {
  const int tid = threadIdx.x;
  const int bid = blockIdx.x;
  const int d   = bid >> 6;
  const int j   = bid & 63;
  const int w   = tid >> 6;
  const int l   = tid & 63;
  const int r15 = l & 15;
  const int kg  = l >> 4;
  const int rt  = w & 1;
  const int ct  = w >> 1;
  const int arow = rt * 16 + r15;

  __shared__ __align__(16) half8 ulds[2 * 16 * 64];   // 32 KB, [ct][kt][l]
  __shared__ __align__(16) half8 wlds[2 * 16 * 64];   // 32 KB
  __shared__ __align__(16) float zlds[32 * 36];
  __shared__ __align__(16) unsigned short hlds[256];

  // Stage this WG's weight fragments into LDS once (rt==0 waves cover both ct).
  {
    const half8* ub = (const half8*)Upk;
    const half8* wb = (const half8*)Wpk;
    const int base = (((d * 64 + j) * 2 + ct) * 16) * 64 + l;
    if (rt == 0) {
#pragma unroll
      for (int kt = 0; kt < 16; ++kt) {
        ulds[(ct * 16 + kt) * 64 + l] = ub[base + kt * 64];
        wlds[(ct * 16 + kt) * 64 + l] = wb[base + kt * 64];
      }
    }
  }

  const int b_e  = tid >> 3;
  const int uu_e = tid & 7;
  const int u_e  = j * 8 + uu_e;
  const int slot_e = (uu_e >> 2) * 16 + (uu_e & 3) * 4;
  f32x4 biasv;
#pragma unroll
  for (int g = 0; g < 4; ++g) biasv[g] = bp.b[4 * d + g][u_e];

  __syncthreads();   // weights staged

  float c = 0.0f;

  for (int s = 0; s < TT; ++s) {
    const int t = d ? (TT - 1 - s) : s;

    // 1) Issue x_t fragment loads (plain; fetch hides under the poll).
    half8 xa[16];
    {
      const half8* xb = (const half8*)(x16 + ((size_t)arow * TT + t) * HH);
#pragma unroll
      for (int kt = 0; kt < 16; ++kt) xa[kt] = xb[kt * 4 + kg];
    }
    __builtin_amdgcn_sched_barrier(0);

    // 2) Poll producer flags (64-lane coalesced; guaranteed by drain+order).
    if (s > 0) {
      if (tid < 64) {
        const int* fl = flags + ((d * 8 + ((s - 1) & 7)) << 6) + tid;
        while (__hip_atomic_load(fl, __ATOMIC_RELAXED, __HIP_MEMORY_SCOPE_AGENT) < s) {
          __builtin_amdgcn_s_sleep(1);
        }
      }
      __syncthreads();
    }
    __builtin_amdgcn_sched_barrier(0);

    // 3) Issue h(s-1) plain dwordx4 loads (XCD-L2 dedup across the 8 same-L2 WGs).
    half8 ha[16];
    if (s > 0) {
      const half8* hb = (const half8*)(h_pk + (size_t)(d * TT + (s - 1)) * 16384);
#pragma unroll
      for (int kt = 0; kt < 16; ++kt) ha[kt] = hb[(kt * 4 + kg) * 32 + arow];
    }
    __builtin_amdgcn_sched_barrier(0);

    // 4) x_t @ W from LDS weights — executes while h loads are in flight.
    f32x4 acc0 = {0,0,0,0}, acc1 = {0,0,0,0}, acc2 = {0,0,0,0}, acc3 = {0,0,0,0};
#pragma unroll
    for (int kt = 0; kt < 16; ++kt) {
      const half8 wk = wlds[(ct * 16 + kt) * 64 + l];
      if ((kt & 3) == 0)      acc0 = __builtin_amdgcn_mfma_f32_16x16x32_f16(xa[kt], wk, acc0, 0, 0, 0);
      else if ((kt & 3) == 1) acc1 = __builtin_amdgcn_mfma_f32_16x16x32_f16(xa[kt], wk, acc1, 0, 0, 0);
      else if ((kt & 3) == 2) acc2 = __builtin_amdgcn_mfma_f32_16x16x32_f16(xa[kt], wk, acc2, 0, 0, 0);
      else                    acc3 = __builtin_amdgcn_mfma_f32_16x16x32_f16(xa[kt], wk, acc3, 0, 0, 0);
    }
    __builtin_amdgcn_sched_barrier(0);

    // 5) h(s-1) @ U from LDS weights.
    if (s > 0) {
#pragma unroll
      for (int kt = 0; kt < 16; ++kt) {
        const half8 uk = ulds[(ct * 16 + kt) * 64 + l];
        if ((kt & 3) == 0)      acc0 = __builtin_amdgcn_mfma_f32_16x16x32_f16(ha[kt], uk, acc0, 0, 0, 0);
        else if ((kt & 3) == 1) acc1 = __builtin_amdgcn_mfma_f32_16x16x32_f16(ha[kt], uk, acc1, 0, 0, 0);
        else if ((kt & 3) == 2) acc2 = __builtin_amdgcn_mfma_f32_16x16x32_f16(ha[kt], uk, acc2, 0, 0, 0);
        else                    acc3 = __builtin_amdgcn_mfma_f32_16x16x32_f16(ha[kt], uk, acc3, 0, 0, 0);
      }
    }
    const f32x4 z = (acc0 + acc1) + (acc2 + acc3);

    // 6) z -> LDS. D-frag: col = r15, row = kg*4 + i.
#pragma unroll
    for (int i = 0; i < 4; ++i)
      zlds[(rt * 16 + kg * 4 + i) * 36 + ct * 16 + r15] = z[i];
    __syncthreads();

    // 7) Elementwise LSTM cell.
    f32x4 pre = *(const f32x4*)&zlds[(size_t)b_e * 36 + slot_e] + biasv;
    const float ig = hsig(pre[0]);
    const float fg = hsig(pre[1]);
    const float gg = fast_tanh(pre[2]);
    const float og = hsig(pre[3]);
    c = fg * c + ig * gg;
    const float h = og * fast_tanh(c);

    hlds[tid] = __builtin_bit_cast(unsigned short, (_Float16)h);
    __syncthreads();

    // 8) Publish: wave 0 stores the WG's contiguous 512 B slice (agent atomic,
    //    IF-visible), drains, then lane 0 sets this WG's epoch flag.
    if (tid < 64) {
      const unsigned long long v = ((const unsigned long long*)hlds)[tid];
      unsigned long long* dst = (unsigned long long*)h_pk +
                                ((size_t)(d * TT + s) * 64 + j) * 64 + tid;
      __hip_atomic_store(dst, v, __ATOMIC_RELAXED, __HIP_MEMORY_SCOPE_AGENT);
      asm volatile("s_waitcnt vmcnt(0)" ::: "memory");
      if (tid == 0)
        __hip_atomic_store(flags + ((d * 8 + (s & 7)) << 6) + j, s + 1,
                           __ATOMIC_RELAXED, __HIP_MEMORY_SCOPE_AGENT);
    }
  }
}

// out[b][t][u] = h_fwd[t] + h_bwd[t]  (Theano: backward stacked in iteration
// order without re-reversing; scan stored bwd iteration s at slot s).
__global__ void sum_out_kernel(const _Float16* __restrict__ h_pk, float* __restrict__ out) {
  const unsigned idx = blockIdx.x * 256 + threadIdx.x;   // 32*512*64
  const int j = idx & 63;
  const int t = (idx >> 6) & 511;
  const int b = idx >> 15;
  half8 hf = ((const half8*)h_pk)[((size_t)t * 64 + j) * 32 + b];
  half8 hg = ((const half8*)h_pk)[((size_t)(TT + t) * 64 + j) * 32 + b];
  float* o = out + (((size_t)b * TT + t) * HH + j * 8);
  float4 r0, r1;
  r0.x = (float)hf[0] + (float)hg[0]; r0.y = (float)hf[1] + (float)hg[1];
  r0.z = (float)hf[2] + (float)hg[2]; r0.w = (float)hf[3] + (float)hg[3];
  r1.x = (float)hf[4] + (float)hg[4]; r1.y = (float)hf[5] + (float)hg[5];
  r1.z = (float)hf[6] + (float)hg[6]; r1.w = (float)hf[7] + (float)hg[7];
  *(float4*)o = r0;
  *(float4*)(o + 4) = r1;
}

extern "C" void kernel_launch(void* const* d_in, const int* in_sizes, int n_in,
                              void* d_out, int out_size, void* d_ws, size_t ws_size,
                              hipStream_t stream) {
  (void)in_sizes; (void)n_in; (void)out_size; (void)ws_size;
  char* ws = (char*)d_ws;
  _Float16* x16   = (_Float16*)ws;
  _Float16* h_pk  = (_Float16*)(ws + OFF_HPK);
  int*      flags = (int*)(ws + OFF_FLAGS);
  _Float16* Upk   = (_Float16*)(ws + OFF_UPK);
  _Float16* Wpk   = (_Float16*)(ws + OFF_WPK);

  convert_x_kernel<<<4096, 256, 0, stream>>>((const float*)d_in[0], x16);

  PackParams pp;
  for (int g = 0; g < 8; ++g) {
    pp.W[g] = (const float*)d_in[1 + g];
    pp.U[g] = (const float*)d_in[9 + g];
  }
  pp.Upk = Upk; pp.Wpk = Wpk;
  pack_frags_kernel<<<16384, 256, 0, stream>>>(pp);

  zero_flags_kernel<<<4, 256, 0, stream>>>(flags);   // 1024 ints, atomic stores

  BiasPtrs bp;
  for (int g = 0; g < 8; ++g) bp.b[g] = (const float*)d_in[17 + g];

  void* args[] = { (void*)&x16, (void*)&h_pk, (void*)&flags,
                   (void*)&Upk, (void*)&Wpk, (void*)&bp };
  hipLaunchCooperativeKernel((const void*)lstm_scan_kernel, dim3(128), dim3(256),
                             args, 0, stream);

  sum_out_kernel<<<4096, 256, 0, stream>>>(h_pk, (float*)d_out);
}